// Round 4
// baseline (844.119 us; speedup 1.0000x reference)
//
#include <hip/hip_runtime.h>

#define BATCH 16
#define LSEQ  2048
#define DDIM  128
#define EPSV  1e-12f
#define NTILE (LSEQ / 64)          // 32 stat-tiles per dim
#define NROWS (BATCH * LSEQ)       // 32768
#define NWORD (LSEQ / 64)          // 32 u64 mask-bit words per row
#define MASKED_NEG (-1e30f)

typedef __attribute__((ext_vector_type(4))) float f32x4;
typedef __attribute__((ext_vector_type(8))) __bf16 bf16x8;
typedef __attribute__((ext_vector_type(8))) unsigned short u16x8;

__device__ __forceinline__ unsigned short f2bf(float x) {
    unsigned int u = __float_as_uint(x);
    u += 0x7FFFu + ((u >> 16) & 1u);
    return (unsigned short)(u >> 16);
}
__device__ __forceinline__ float bf2f(unsigned short h) {
    return __uint_as_float(((unsigned int)h) << 16);
}

// direct-to-LDS copy of one 16B slot per lane (LDS dest linear, source pre-swizzled)
__device__ __forceinline__ void gll16(const unsigned short* src, unsigned short* ldsdst) {
    __builtin_amdgcn_global_load_lds(
        (const __attribute__((address_space(1))) void*)src,
        (__attribute__((address_space(3))) void*)ldsdst, 16, 0, 0);
}

// ---------------------------------------------------------------------------
// K0a: elementwise fp32 -> bf16 hi/lo split for Q (blockIdx.y=0) and K (=1).
// ---------------------------------------------------------------------------
__global__ __launch_bounds__(256) void k0_split(
    const float* __restrict__ q, const float* __restrict__ kmat,
    unsigned short* __restrict__ qh, unsigned short* __restrict__ ql,
    unsigned short* __restrict__ kh, unsigned short* __restrict__ kl)
{
    const float* s     = blockIdx.y ? kmat : q;
    unsigned short* ph = blockIdx.y ? kh : qh;
    unsigned short* pl = blockIdx.y ? kl : ql;
    const size_t i = ((size_t)blockIdx.x * 256 + threadIdx.x) << 3;
    float xs[8];
    *(float4*)&xs[0] = *(const float4*)(s + i);
    *(float4*)&xs[4] = *(const float4*)(s + i + 4);
    u16x8 hh, ll;
#pragma unroll
    for (int e = 0; e < 8; ++e) {
        const unsigned short h = f2bf(xs[e]);
        hh[e] = h;
        ll[e] = f2bf(xs[e] - bf2f(h));
    }
    *(u16x8*)(ph + i) = hh;
    *(u16x8*)(pl + i) = ll;
}

// ---------------------------------------------------------------------------
// K0b: V[b][j][dv] -> Vt planes (bf16 hi/lo) [b][dv][j]
// ---------------------------------------------------------------------------
__global__ __launch_bounds__(256) void k0_vtrans(
    const float* __restrict__ v,
    unsigned short* __restrict__ vth, unsigned short* __restrict__ vtl)
{
    const int b  = blockIdx.z;
    const int j0 = blockIdx.x * 64;
    const int d0 = blockIdx.y * 64;
    __shared__ float T[64][65];

    const int tid = threadIdx.x;
    {
        const int jr = tid >> 4;
        const int c4 = (tid & 15) << 2;
#pragma unroll
        for (int p = 0; p < 4; ++p) {
            const int row = jr + (p << 4);
            *(float4*)&T[row][c4] =
                *(const float4*)(v + ((size_t)b * LSEQ + j0 + row) * DDIM + d0 + c4);
        }
    }
    __syncthreads();

    const int dr = tid >> 2;
    const int jc = (tid & 3) << 4;
    u16x8 h[2], l[2];
#pragma unroll
    for (int e = 0; e < 16; ++e) {
        const float x = T[jc + e][dr];
        const unsigned short hh = f2bf(x);
        h[e >> 3][e & 7] = hh;
        l[e >> 3][e & 7] = f2bf(x - bf2f(hh));
    }
    unsigned short* oh = vth + ((size_t)b * DDIM + d0 + dr) * LSEQ + j0 + jc;
    unsigned short* ol = vtl + ((size_t)b * DDIM + d0 + dr) * LSEQ + j0 + jc;
    *(u16x8*)oh = h[0]; *(u16x8*)(oh + 8) = h[1];
    *(u16x8*)ol = l[0]; *(u16x8*)(ol + 8) = l[1];
}

// ---------------------------------------------------------------------------
// K0c: pack mask (0/1 fp32) into bit-words: bits[row][j/64], bit j&63.
// One wave per row, ballot per 64-j group.
// ---------------------------------------------------------------------------
__global__ __launch_bounds__(256) void k0_pack(
    const float* __restrict__ mask, unsigned long long* __restrict__ bits)
{
    const int tid  = threadIdx.x;
    const int lane = tid & 63;
    const int w    = tid >> 6;
    const size_t row = (size_t)blockIdx.x * 4 + w;
    const float* mr = mask + row * LSEQ;
    unsigned long long* br = bits + row * NWORD;
#pragma unroll 4
    for (int j = 0; j < LSEQ; j += 64) {
        const unsigned long long m = __ballot(mr[j + lane] != 0.f);
        if (lane == 0) br[j >> 6] = m;
    }
}

// ---------------------------------------------------------------------------
// K1: stats-only pass.  x = Q K^T via bf16x3 MFMA (planes + gll staging);
// per-64x64-tile row/col max (raw) and masked exp-sums (mask from bit-words).
// NO attn materialization — K3 recomputes x bit-identically.
// ---------------------------------------------------------------------------
__global__ __launch_bounds__(256, 2) void k1_qk_stats(
    const unsigned short* __restrict__ qh, const unsigned short* __restrict__ ql,
    const unsigned short* __restrict__ kh, const unsigned short* __restrict__ kl,
    const unsigned long long* __restrict__ bits,
    float* __restrict__ rowMt, float* __restrict__ rowSt,
    float* __restrict__ colMt, float* __restrict__ colSt)
{
    const int b  = blockIdx.z;
    const int it = blockIdx.y * 128;
    const int jt = blockIdx.x * 128;

    __shared__ __attribute__((aligned(16))) unsigned short smem[4 * 128 * 64]; // 64 KB
    unsigned short* Ah = smem;
    unsigned short* Al = smem + 8192;
    unsigned short* Bh = smem + 16384;
    unsigned short* Bl = smem + 24576;

    const int tid  = threadIdx.x;
    const int lane = tid & 63;
    const int w    = tid >> 6;
    const int wrow = (w >> 1) << 6;
    const int wcol = (w & 1) << 6;
    const int g    = lane >> 4;
    const int cl   = lane & 15;

    const unsigned short* splane = (w == 0) ? qh : (w == 1) ? ql : (w == 2) ? kh : kl;
    const size_t srow0 = (size_t)b * LSEQ + ((w < 2) ? it : jt);
    unsigned short* dplane = smem + w * 8192;
    const int srow = lane >> 3;
    const int sslt = lane & 7;

    f32x4 acc[4][4];
    const f32x4 zero = {0.f, 0.f, 0.f, 0.f};
#pragma unroll
    for (int i = 0; i < 4; ++i)
#pragma unroll
        for (int j = 0; j < 4; ++j) acc[i][j] = zero;

#pragma unroll
    for (int half = 0; half < 2; ++half) {
        const int ks2 = half << 6;
        if (half) __syncthreads();
#pragma unroll
        for (int qq = 0; qq < 16; ++qq) {
            const int row = (qq << 3) + srow;
            const int ss  = sslt ^ (row & 7);
            gll16(splane + (srow0 + row) * DDIM + ks2 + (ss << 3),
                  dplane + (qq << 9));
        }
        __syncthreads();

#pragma unroll
        for (int ks = 0; ks < 64; ks += 32) {
            const int colb = ks + (g << 3);
            bf16x8 ah[4], al[4], bh[4], bl[4];
#pragma unroll
            for (int f = 0; f < 4; ++f) {
                const int ra = wrow + (f << 4) + cl;
                const int rb = wcol + (f << 4) + cl;
                const int oa = (ra << 6) + ((((colb >> 3) ^ ra) & 7) << 3);
                const int ob = (rb << 6) + ((((colb >> 3) ^ rb) & 7) << 3);
                ah[f] = __builtin_bit_cast(bf16x8, *(const u16x8*)&Ah[oa]);
                al[f] = __builtin_bit_cast(bf16x8, *(const u16x8*)&Al[oa]);
                bh[f] = __builtin_bit_cast(bf16x8, *(const u16x8*)&Bh[ob]);
                bl[f] = __builtin_bit_cast(bf16x8, *(const u16x8*)&Bl[ob]);
            }
#pragma unroll
            for (int fr = 0; fr < 4; ++fr)
#pragma unroll
                for (int fc = 0; fc < 4; ++fc) {
                    acc[fr][fc] = __builtin_amdgcn_mfma_f32_16x16x32_bf16(ah[fr], bh[fc], acc[fr][fc], 0, 0, 0);
                    acc[fr][fc] = __builtin_amdgcn_mfma_f32_16x16x32_bf16(ah[fr], bl[fc], acc[fr][fc], 0, 0, 0);
                    acc[fr][fc] = __builtin_amdgcn_mfma_f32_16x16x32_bf16(al[fr], bh[fc], acc[fr][fc], 0, 0, 0);
                }
        }
    }

    // ---- mask bit-words for this wave's 64x64 tile (broadcast u64 loads) ----
    unsigned long long wb[4][4];
#pragma unroll
    for (int fr = 0; fr < 4; ++fr)
#pragma unroll
        for (int r = 0; r < 4; ++r)
            wb[fr][r] = bits[((size_t)b * LSEQ + it + wrow + (fr << 4) + (g << 2) + r)
                             * NWORD + ((jt + wcol) >> 6)];

    // ---- per-tile stats (pure shuffles), max over RAW x, sums over masked ----
    float colm[4];
#pragma unroll
    for (int fc = 0; fc < 4; ++fc) {
        float m = acc[0][fc][0];
#pragma unroll
        for (int fr = 0; fr < 4; ++fr)
#pragma unroll
            for (int r = 0; r < 4; ++r) m = fmaxf(m, acc[fr][fc][r]);
        m = fmaxf(m, __shfl_xor(m, 16, 64));
        m = fmaxf(m, __shfl_xor(m, 32, 64));
        colm[fc] = m;
    }
    float rowm[4][4];
#pragma unroll
    for (int fr = 0; fr < 4; ++fr)
#pragma unroll
        for (int r = 0; r < 4; ++r) {
            float m = fmaxf(fmaxf(acc[fr][0][r], acc[fr][1][r]),
                            fmaxf(acc[fr][2][r], acc[fr][3][r]));
            m = fmaxf(m, __shfl_xor(m, 1, 64));
            m = fmaxf(m, __shfl_xor(m, 2, 64));
            m = fmaxf(m, __shfl_xor(m, 4, 64));
            m = fmaxf(m, __shfl_xor(m, 8, 64));
            rowm[fr][r] = m;
        }

    float cols_[4] = {0.f, 0.f, 0.f, 0.f};
    float rows_[4][4];
#pragma unroll
    for (int fr = 0; fr < 4; ++fr) {
#pragma unroll
        for (int r = 0; r < 4; ++r) {
            const float rm = rowm[fr][r];
            float rs = 0.f;
#pragma unroll
            for (int fc = 0; fc < 4; ++fc) {
                const float x  = acc[fr][fc][r];
                const float xp = ((wb[fr][r] >> ((fc << 4) + cl)) & 1ULL) ? x : MASKED_NEG;
                rs        += __expf(xp - rm);
                cols_[fc] += __expf(xp - colm[fc]);
            }
            rs += __shfl_xor(rs, 1, 64);
            rs += __shfl_xor(rs, 2, 64);
            rs += __shfl_xor(rs, 4, 64);
            rs += __shfl_xor(rs, 8, 64);
            rows_[fr][r] = rs;
        }
    }
#pragma unroll
    for (int fc = 0; fc < 4; ++fc) {
        float s = cols_[fc];
        s += __shfl_xor(s, 16, 64);
        s += __shfl_xor(s, 32, 64);
        cols_[fc] = s;
    }

    const int ti = (blockIdx.y << 1) + (w >> 1);
    const int tj = (blockIdx.x << 1) + (w & 1);
    if (cl == 0) {
        const size_t rbase = (size_t)tj * NROWS + (size_t)b * LSEQ + it + wrow;
#pragma unroll
        for (int fr = 0; fr < 4; ++fr)
#pragma unroll
            for (int r = 0; r < 4; ++r) {
                const int R = (fr << 4) + (g << 2) + r;
                rowMt[rbase + R] = rowm[fr][r];
                rowSt[rbase + R] = rows_[fr][r];
            }
    }
    if (g == 0) {
        const size_t cbase = (size_t)ti * NROWS + (size_t)b * LSEQ + jt + wcol;
#pragma unroll
        for (int fc = 0; fc < 4; ++fc) {
            colMt[cbase + (fc << 4) + cl] = colm[fc];
            colSt[cbase + (fc << 4) + cl] = cols_[fc];
        }
    }
}

// ---------------------------------------------------------------------------
// K2: combine per-tile stats -> global max & INVERSE sum per row / col.
// ---------------------------------------------------------------------------
__global__ __launch_bounds__(256) void k2_combine(
    const float* __restrict__ rowMt, const float* __restrict__ rowSt,
    const float* __restrict__ colMt, const float* __restrict__ colSt,
    float* __restrict__ rmaxf, float* __restrict__ rinvf,
    float* __restrict__ cmaxf, float* __restrict__ cinvf)
{
    const int id = blockIdx.x * 256 + threadIdx.x;
    const bool isRow = (id < NROWS);
    const int off = isRow ? id : id - NROWS;
    const float* Mt = isRow ? rowMt : colMt;
    const float* St = isRow ? rowSt : colSt;

    float m = -INFINITY;
#pragma unroll
    for (int t = 0; t < NTILE; ++t) m = fmaxf(m, Mt[(size_t)t * NROWS + off]);
    float s = 0.f;
#pragma unroll
    for (int t = 0; t < NTILE; ++t)
        s += St[(size_t)t * NROWS + off] * __expf(Mt[(size_t)t * NROWS + off] - m);
    const float inv = 1.f / (s + EPSV);

    if (isRow) { rmaxf[off] = m; rinvf[off] = inv; }
    else       { cmaxf[off] = m; cinvf[off] = inv; }
}

// ---------------------------------------------------------------------------
// K3: recompute x = Q K^T (bit-identical MFMA chain to K1), gate with bits +
// global stats, write exact fp32 gated, and PV-MFMA into out.
// Block = 64 q-rows; 4 waves: wave owns 16 q-rows for QK^T/gating, and the
// dv-slice w*32..w*32+31 of ALL 64 rows for PV.  j in chunks of 64.
// LDS 80 KB -> 2 blocks/CU.  Q frags persist in registers.
// ---------------------------------------------------------------------------
__global__ __launch_bounds__(256) void k3_gated_out(
    const unsigned short* __restrict__ qh, const unsigned short* __restrict__ ql,
    const unsigned short* __restrict__ kh, const unsigned short* __restrict__ kl,
    const unsigned short* __restrict__ vth, const unsigned short* __restrict__ vtl,
    const unsigned long long* __restrict__ bits,
    const float* __restrict__ rmaxf, const float* __restrict__ cmaxf,
    const float* __restrict__ rinvf, const float* __restrict__ cinvf,
    float* __restrict__ gated, float* __restrict__ outp)
{
    const int b   = blockIdx.y;
    const int it0 = blockIdx.x * 64;

    __shared__ __attribute__((aligned(16))) unsigned short Kh_[64 * 128]; // 16 KB
    __shared__ __attribute__((aligned(16))) unsigned short Kl_[64 * 128];
    __shared__ __attribute__((aligned(16))) unsigned short Vh_[128 * 64]; // 16 KB
    __shared__ __attribute__((aligned(16))) unsigned short Vl_[128 * 64];
    __shared__ __attribute__((aligned(16))) unsigned short Gh_[64 * 64];  // 8 KB
    __shared__ __attribute__((aligned(16))) unsigned short Gl_[64 * 64];

    const int tid  = threadIdx.x;
    const int lane = tid & 63;
    const int w    = tid >> 6;
    const int g    = lane >> 4;
    const int cl   = lane & 15;

    // ---- stage Q strip [64][128] hi/lo into Kh_/Kl_ (one-time), frags -> regs
#pragma unroll
    for (int p = 0; p < 4; ++p) {
        const int op  = (w << 2) + p;
        const int row = (op << 2) + (lane >> 4);
        const int ss  = (lane & 15) ^ (row & 15);
        gll16(qh + ((size_t)b * LSEQ + it0 + row) * DDIM + (ss << 3), Kh_ + (op << 9));
        gll16(ql + ((size_t)b * LSEQ + it0 + row) * DDIM + (ss << 3), Kl_ + (op << 9));
    }
    __syncthreads();

    bf16x8 aqh[4], aql[4];
    {
        const int row = (w << 4) + cl;
#pragma unroll
        for (int ks = 0; ks < 4; ++ks) {
            const int slt = (((ks << 2) + g) ^ (row & 15));
            aqh[ks] = __builtin_bit_cast(bf16x8, *(const u16x8*)&Kh_[(row << 7) + (slt << 3)]);
            aql[ks] = __builtin_bit_cast(bf16x8, *(const u16x8*)&Kl_[(row << 7) + (slt << 3)]);
        }
    }
    float mrw[4], irw[4];
#pragma unroll
    for (int r = 0; r < 4; ++r) {
        const int R = it0 + (w << 4) + (g << 2) + r;
        mrw[r] = rmaxf[b * LSEQ + R];
        irw[r] = rinvf[b * LSEQ + R];
    }

    f32x4 oacc[4][2];
    const f32x4 zero = {0.f, 0.f, 0.f, 0.f};
#pragma unroll
    for (int qf = 0; qf < 4; ++qf) { oacc[qf][0] = zero; oacc[qf][1] = zero; }

    __syncthreads();   // Q frag reads complete before chunk staging overwrites

#pragma unroll 1
    for (int j0 = 0; j0 < LSEQ; j0 += 64) {
        // ---- stage K chunk [64][128] + Vt chunk [128][64] (hi/lo) ----
#pragma unroll
        for (int p = 0; p < 4; ++p) {
            const int op = (w << 2) + p;
            const int rk = (op << 2) + (lane >> 4);
            const int sk = (lane & 15) ^ (rk & 15);
            gll16(kh + ((size_t)b * LSEQ + j0 + rk) * DDIM + (sk << 3), Kh_ + (op << 9));
            gll16(kl + ((size_t)b * LSEQ + j0 + rk) * DDIM + (sk << 3), Kl_ + (op << 9));
            const int rv = (op << 3) + (lane >> 3);
            const int sv = (lane & 7) ^ (rv & 7);
            gll16(vth + ((size_t)b * DDIM + rv) * LSEQ + j0 + (sv << 3), Vh_ + (op << 9));
            gll16(vtl + ((size_t)b * DDIM + rv) * LSEQ + j0 + (sv << 3), Vl_ + (op << 9));
        }
        __syncthreads();               // staged (full drain before barrier)

        // ---- QK^T: rows w*16.., cols j0..j0+63 (same chain order as K1) ----
        f32x4 xacc[4];
#pragma unroll
        for (int jf = 0; jf < 4; ++jf) xacc[jf] = zero;
#pragma unroll
        for (int ks = 0; ks < 4; ++ks) {
            bf16x8 bh[4], bl[4];
#pragma unroll
            for (int jf = 0; jf < 4; ++jf) {
                const int rb  = (jf << 4) + cl;
                const int slt = (((ks << 2) + g) ^ (rb & 15));
                bh[jf] = __builtin_bit_cast(bf16x8, *(const u16x8*)&Kh_[(rb << 7) + (slt << 3)]);
                bl[jf] = __builtin_bit_cast(bf16x8, *(const u16x8*)&Kl_[(rb << 7) + (slt << 3)]);
            }
#pragma unroll
            for (int jf = 0; jf < 4; ++jf) {
                xacc[jf] = __builtin_amdgcn_mfma_f32_16x16x32_bf16(aqh[ks], bh[jf], xacc[jf], 0, 0, 0);
                xacc[jf] = __builtin_amdgcn_mfma_f32_16x16x32_bf16(aqh[ks], bl[jf], xacc[jf], 0, 0, 0);
                xacc[jf] = __builtin_amdgcn_mfma_f32_16x16x32_bf16(aql[ks], bh[jf], xacc[jf], 0, 0, 0);
            }
        }

        // ---- gate: gated = exp(2x' - mr - mc) * ir * ic; G -> LDS bf16 hi/lo
        unsigned long long wb[4];
#pragma unroll
        for (int r = 0; r < 4; ++r)
            wb[r] = bits[((size_t)b * LSEQ + it0 + (w << 4) + (g << 2) + r) * NWORD + (j0 >> 6)];
        float* gbase = gated + ((size_t)b * LSEQ + it0 + (w << 4) + (g << 2)) * LSEQ + j0;
#pragma unroll
        for (int jf = 0; jf < 4; ++jf) {
            const int c = (jf << 4) + cl;
            const float cmv = cmaxf[b * LSEQ + j0 + c];
            const float civ = cinvf[b * LSEQ + j0 + c];
#pragma unroll
            for (int r = 0; r < 4; ++r) {
                const float x  = xacc[jf][r];
                const float xp = ((wb[r] >> c) & 1ULL) ? x : MASKED_NEG;
                const float gv = __expf(2.f * xp - mrw[r] - cmv) * irw[r] * civ;
                gbase[(size_t)r * LSEQ + c] = gv;
                const unsigned short hb = f2bf(gv);
                const unsigned short lb = f2bf(gv - bf2f(hb));
                const int grow = (w << 4) + (g << 2) + r;
                const int gidx = (grow << 6) + (((((jf << 1) + (cl >> 3)) ^ grow) & 7) << 3) + (cl & 7);
                Gh_[gidx] = hb;
                Gl_[gidx] = lb;
            }
        }
        __syncthreads();               // G ready

        // ---- PV: out rows 0..63, dv slice w*32..w*32+31 ----
#pragma unroll
        for (int kc = 0; kc < 2; ++kc) {
            bf16x8 agh[4], agl[4];
#pragma unroll
            for (int qf = 0; qf < 4; ++qf) {
                const int ra  = (qf << 4) + cl;
                const int slt = (((kc << 2) + g) ^ (ra & 7));
                agh[qf] = __builtin_bit_cast(bf16x8, *(const u16x8*)&Gh_[(ra << 6) + (slt << 3)]);
                agl[qf] = __builtin_bit_cast(bf16x8, *(const u16x8*)&Gl_[(ra << 6) + (slt << 3)]);
            }
#pragma unroll
            for (int nf = 0; nf < 2; ++nf) {
                const int rb  = (w << 5) + (nf << 4) + cl;
                const int slt = (((kc << 2) + g) ^ (rb & 7));
                const bf16x8 bvh = __builtin_bit_cast(bf16x8, *(const u16x8*)&Vh_[(rb << 6) + (slt << 3)]);
                const bf16x8 bvl = __builtin_bit_cast(bf16x8, *(const u16x8*)&Vl_[(rb << 6) + (slt << 3)]);
#pragma unroll
                for (int qf = 0; qf < 4; ++qf) {
                    oacc[qf][nf] = __builtin_amdgcn_mfma_f32_16x16x32_bf16(agh[qf], bvh, oacc[qf][nf], 0, 0, 0);
                    oacc[qf][nf] = __builtin_amdgcn_mfma_f32_16x16x32_bf16(agl[qf], bvh, oacc[qf][nf], 0, 0, 0);
                    oacc[qf][nf] = __builtin_amdgcn_mfma_f32_16x16x32_bf16(agh[qf], bvl, oacc[qf][nf], 0, 0, 0);
                }
            }
        }
        __syncthreads();               // PV done; LDS free for next staging
    }

    float* ob = outp + ((size_t)b * LSEQ + it0) * DDIM + (w << 5);
#pragma unroll
    for (int qf = 0; qf < 4; ++qf)
#pragma unroll
        for (int r = 0; r < 4; ++r) {
            const int R = (qf << 4) + (g << 2) + r;
#pragma unroll
            for (int nf = 0; nf < 2; ++nf)
                ob[(size_t)R * DDIM + (nf << 4) + cl] = oacc[qf][nf][r];
        }
}

// ---------------------------------------------------------------------------
extern "C" void kernel_launch(void* const* d_in, const int* in_sizes, int n_in,
                              void* d_out, int out_size, void* d_ws, size_t ws_size,
                              hipStream_t stream)
{
    (void)in_sizes; (void)n_in; (void)out_size; (void)ws_size;
    const float* q    = (const float*)d_in[0];
    const float* k    = (const float*)d_in[1];
    const float* v    = (const float*)d_in[2];
    const float* mask = (const float*)d_in[3];

    float* outp  = (float*)d_out;                                   // B*L*D
    float* gated = (float*)d_out + (size_t)BATCH * LSEQ * DDIM;     // B*L*L

    // workspace: bits first (8B aligned), then fp32 stats, then bf16 planes
    unsigned long long* bitsw = (unsigned long long*)d_ws;           // [NROWS][NWORD]
    float* rowMt = (float*)(bitsw + (size_t)NROWS * NWORD);          // [NTILE][NROWS]
    float* rowSt = rowMt + (size_t)NTILE * NROWS;
    float* colMt = rowSt + (size_t)NTILE * NROWS;
    float* colSt = colMt + (size_t)NTILE * NROWS;
    float* rmaxf = colSt + (size_t)NTILE * NROWS;
    float* rinvf = rmaxf + NROWS;
    float* cmaxf = rinvf + NROWS;
    float* cinvf = cmaxf + NROWS;
    unsigned short* vth = (unsigned short*)(cinvf + NROWS);          // [B][D][L]
    unsigned short* vtl = vth + (size_t)BATCH * DDIM * LSEQ;
    unsigned short* qhp = vtl + (size_t)BATCH * DDIM * LSEQ;         // [B][L][D]
    unsigned short* qlp = qhp + (size_t)BATCH * LSEQ * DDIM;
    unsigned short* khp = qlp + (size_t)BATCH * LSEQ * DDIM;
    unsigned short* klp = khp + (size_t)BATCH * LSEQ * DDIM;

    dim3 gsplit((BATCH * LSEQ * DDIM) / 2048, 2);
    k0_split<<<gsplit, dim3(256), 0, stream>>>(q, k, qhp, qlp, khp, klp);

    dim3 g0(LSEQ / 64, DDIM / 64, BATCH);
    k0_vtrans<<<g0, dim3(256), 0, stream>>>(v, vth, vtl);

    k0_pack<<<dim3(NROWS / 4), dim3(256), 0, stream>>>(mask, bitsw);

    dim3 g1(LSEQ / 128, LSEQ / 128, BATCH);
    k1_qk_stats<<<g1, dim3(256), 0, stream>>>(qhp, qlp, khp, klp, bitsw,
                                              rowMt, rowSt, colMt, colSt);

    k2_combine<<<dim3(2 * NROWS / 256), dim3(256), 0, stream>>>(
        rowMt, rowSt, colMt, colSt, rmaxf, rinvf, cmaxf, cinvf);

    dim3 g3(LSEQ / 64, BATCH);
    k3_gated_out<<<g3, dim3(256), 0, stream>>>(qhp, qlp, khp, klp, vth, vtl, bitsw,
                                               rmaxf, cmaxf, rinvf, cinvf,
                                               gated, outp);
}